// Round 13
// baseline (3083.865 us; speedup 1.0000x reference)
//
#include <hip/hip_runtime.h>

typedef _Float16 half8  __attribute__((ext_vector_type(8)));
typedef _Float16 half4v __attribute__((ext_vector_type(4)));
typedef float    floatx4 __attribute__((ext_vector_type(4)));
typedef unsigned long long u64;

#define B_ 32
#define S_ 512
#define I_ 1024
#define H_ 1024
#define M_TOT (B_ * S_)       // 16384
#define RING_HALVES (3 * 2 * B_ * H_)   // 196608 halves per ring (3 slots)
#define RING_U32    (RING_HALVES / 2)   // 98304 u32 per ring

// ---------------------------------------------------------------------------
__global__ void cvt_f32_f16(const float* __restrict__ src, _Float16* __restrict__ dst, long n) {
  long i = ((long)blockIdx.x * blockDim.x + threadIdx.x) * 4;
  const long stride = (long)gridDim.x * blockDim.x * 4;
  for (; i < n; i += stride) {
    floatx4 v = *(const floatx4*)(src + i);
    half4v h = {(_Float16)v[0], (_Float16)v[1], (_Float16)v[2], (_Float16)v[3]};
    *(half4v*)(dst + i) = h;
  }
}

__global__ void bias_sum_kernel(const float* __restrict__ bihf, const float* __restrict__ bhhf,
                                const float* __restrict__ bihb, const float* __restrict__ bhhb,
                                float* __restrict__ bias) {
  int i = blockIdx.x * blockDim.x + threadIdx.x;
  if (i < H_) {
    bias[i]      = bihf[i] + bhhf[i];
    bias[H_ + i] = bihb[i] + bhhb[i];
  }
}

// ---------------------------------------------------------------------------
// Ring init (every launch -> replay-deterministic), BOTH rings (mall + loc):
// slot0 = h[0] zeros (LSB 0 = tag of t=0); slot1 = 0x0002 halves (LSB 0 != 1);
// slot2 = 0x0001 halves (LSB 1 != 0). sc1 stores; the scan's sc0 loads fetch
// through (kernel-boundary L2 invalidate is proven by GEMM->scan visibility).
// ---------------------------------------------------------------------------
__global__ void init_ring(unsigned int* __restrict__ hq) {
  const int i = blockIdx.x * blockDim.x + threadIdx.x;   // 0..196607 (2 rings)
  const int j = (i >= RING_U32) ? (i - RING_U32) : i;
  unsigned int v = 0u;
  if (j >= 32768) v = (j < 65536) ? 0x00020002u : 0x00010001u;
  __hip_atomic_store(hq + i, v, __ATOMIC_RELAXED, __HIP_MEMORY_SCOPE_AGENT);
}

// ---------------------------------------------------------------------------
// GEMM (unchanged, proven): xp -> out in place.
// ---------------------------------------------------------------------------
__global__ void __launch_bounds__(256) gemm_xp_kernel(
    const _Float16* __restrict__ A,
    const _Float16* __restrict__ W,
    const float*    __restrict__ bias,
    float*          __restrict__ out)
{
  __shared__ _Float16 alds[128 * 32];
  __shared__ _Float16 blds[128 * 32];

  const int dir = blockIdx.z;
  const int m0  = blockIdx.y * 128;
  const int n0  = blockIdx.x * 128;
  const int tid  = threadIdx.x;
  const int lane = tid & 63;
  const int wv   = tid >> 6;
  const int wm   = wv >> 1, wn = wv & 1;
  const int lrow = lane & 15;
  const int lkg  = lane >> 4;

  const _Float16* Wd = W + (long)dir * H_ * I_;

  floatx4 acc[4][4] = {};

  const int srow = tid >> 1;
  const int sseg = tid & 1;

  for (int kt = 0; kt < 32; ++kt) {
    __syncthreads();
    {
      const _Float16* srcA = A  + (long)(m0 + srow) * I_ + kt * 32 + sseg * 16;
      const _Float16* srcB = Wd + (long)(n0 + srow) * I_ + kt * 32 + sseg * 16;
      half8 a0 = *(const half8*)(srcA);
      half8 a1 = *(const half8*)(srcA + 8);
      half8 b0 = *(const half8*)(srcB);
      half8 b1 = *(const half8*)(srcB + 8);
      const int sw = (srow & 7) << 4;
      const int base = srow * 64 + sseg * 32;
      *(half8*)((char*)alds + ((base     ) ^ sw)) = a0;
      *(half8*)((char*)alds + ((base + 16) ^ sw)) = a1;
      *(half8*)((char*)blds + ((base     ) ^ sw)) = b0;
      *(half8*)((char*)blds + ((base + 16) ^ sw)) = b1;
    }
    __syncthreads();

    half8 af[4], bf[4];
#pragma unroll
    for (int mt = 0; mt < 4; ++mt) {
      int r = wm * 64 + mt * 16 + lrow;
      int byte = (r * 64 + lkg * 16) ^ ((r & 7) << 4);
      af[mt] = *(const half8*)((const char*)alds + byte);
    }
#pragma unroll
    for (int ntt = 0; ntt < 4; ++ntt) {
      int r = wn * 64 + ntt * 16 + lrow;
      int byte = (r * 64 + lkg * 16) ^ ((r & 7) << 4);
      bf[ntt] = *(const half8*)((const char*)blds + byte);
    }
#pragma unroll
    for (int mt = 0; mt < 4; ++mt)
#pragma unroll
      for (int ntt = 0; ntt < 4; ++ntt)
        acc[mt][ntt] = __builtin_amdgcn_mfma_f32_16x16x32_f16(af[mt], bf[ntt], acc[mt][ntt], 0, 0, 0);
  }

#pragma unroll
  for (int mt = 0; mt < 4; ++mt) {
    int mrow = m0 + wm * 64 + mt * 16 + lkg * 4;
#pragma unroll
    for (int ntt = 0; ntt < 4; ++ntt) {
      int n = n0 + wn * 64 + ntt * 16 + lrow;
      float bv = bias[dir * H_ + n];
#pragma unroll
      for (int v = 0; v < 4; ++v) {
        out[(long)(mrow + v) * (2 * H_) + dir * H_ + n] = acc[mt][ntt][v] + bv;
      }
    }
  }
}

// ---------------------------------------------------------------------------
// Recurrent scan, dual-ring edition (R11 protocol + XCD-local fast path with
// bounded-retry fallback -- deadlock-impossible by construction).
// Grid 256, active iff blockIdx%8 < 2: dir = blockIdx%8, rb = blockIdx>>3.
// Under round-robin dispatch each direction's 32 WGs share one XCD; if not,
// the fallback engages automatically.
// Producers dual-store each LSB-tagged 8B h granule:
//   plain store  -> LOCAL ring (own XCD L2)         [fast path data]
//   sc1 store    -> MALL ring (device coherent)      [fallback, proven R11]
// Consumers: tag-check loads from LOCAL ring via sc0 (L1-bypass, L2-served).
// After 128 failed attempts in a step, the wave PERMANENTLY switches to the
// MALL ring (sc1 loads) -- guaranteed progress (R11-proven). No XCC reads,
// no votes, no fences, no cross-scope aliasing (two disjoint buffers).
// Ring-3 + LSB-tag safety proof unchanged from R11.
// ---------------------------------------------------------------------------
__global__ void __launch_bounds__(256, 1) scan_kernel(
    const float* __restrict__ Whh_f,
    const float* __restrict__ Whh_b,
    float*       __restrict__ out,     // [B][S][2H]; holds xp on entry
    _Float16*    __restrict__ hmall,   // [3][2][B][H] f16 MALL ring
    _Float16*    __restrict__ hloc)    // [3][2][B][H] f16 local-L2 ring
{
  __shared__ _Float16 wlds[32 * 1024];     // 64 KiB
  __shared__ floatx4  redlds[2 * 4 * 64];  // 8 KiB, parity-double-buffered

  const int g = blockIdx.x & 7;
  if (g >= 2) return;
  const int dir = g;
  const int rb  = blockIdx.x >> 3;   // 0..31
  const int rows0 = rb * 32;
  const float* Whh = dir ? Whh_b : Whh_f;
  const int tid = threadIdx.x;

  // stage W_hh rows [rows0, rows0+32) as f16, swizzled: byte ^= (row&7)<<4
  for (int idx = tid; idx < 32 * 128; idx += 256) {
    const int r  = idx >> 7;
    const int kg = idx & 127;
    const float* src = Whh + (long)(rows0 + r) * H_ + kg * 8;
    floatx4 v0 = *(const floatx4*)(src);
    floatx4 v1 = *(const floatx4*)(src + 4);
    half8 h = {(_Float16)v0[0], (_Float16)v0[1], (_Float16)v0[2], (_Float16)v0[3],
               (_Float16)v1[0], (_Float16)v1[1], (_Float16)v1[2], (_Float16)v1[3]};
    const int byte = (r * 2048 + kg * 16) ^ ((r & 7) << 4);
    *(half8*)((char*)wlds + byte) = h;
  }

  // wave/lane roles (R11)
  const int lane = tid & 63;
  const int wv   = tid >> 6;
  const int nt   = wv & 1;          // batch half
  const int kh   = wv >> 1;         // K half / owned row tile
  const int lrow = lane & 15;
  const int lkg  = lane >> 4;       // 0..3
  const int b_idx = nt * 16 + lrow; // batch
  const int kbase = kh * 512;       // K-half start (halves)
  const int r0    = rows0 + kh * 16 + lkg * 4;  // this lane's 4 output rows
  const int asw   = (lrow & 7) << 4;
  const int abase0 = lrow * 2048 + kbase * 2;        // tile0 row byte base
  const int abase1 = (16 + lrow) * 2048 + kbase * 2; // tile1 row byte base

  const long hstride = (long)2 * B_ * H_;  // slot stride in halves
  const long inoff_base = ((long)dir * B_ + b_idx) * H_ + kbase + lkg * 8;
  const long outoff_base = ((long)dir * B_ + b_idx) * H_ + r0;

  __syncthreads();  // W LDS visible to all waves

  // 1-step-ahead xp prefetch (own cells only)
  long o_nxt = ((long)b_idx * S_ + (dir ? (S_ - 1) : 0)) * (2 * H_) + dir * H_ + r0;
  floatx4 xp_n = *(const floatx4*)(out + o_nxt);

  int s_in = 0;        // slot of h[t]
  int use_mall = 0;    // sticky per-wave fallback flag

#pragma unroll 1
  for (int t = 0; t < S_; ++t) {
    const int p = t & 1;
    const int s_out = (s_in == 2) ? 0 : (s_in + 1);

    // ---- speculative tag-checked h loads: freshness == data ----
    const _Float16* lp = hloc  + (s_in * hstride) + inoff_base;
    const _Float16* mp = hmall + (s_in * hstride) + inoff_base;
    const unsigned int rep = (unsigned)(t & 1) * 0x00010001u;
    half8 hr[16];
    int att = 0;
    for (;;) {
      if (use_mall) {
#pragma unroll
        for (int kt = 0; kt < 16; ++kt)
          asm volatile("global_load_dwordx4 %0, %1, off offset:%2 sc1"
                       : "=v"(hr[kt]) : "v"(mp), "i"(kt * 64) : "memory");
      } else {
#pragma unroll
        for (int kt = 0; kt < 16; ++kt)
          asm volatile("global_load_dwordx4 %0, %1, off offset:%2 sc0"
                       : "=v"(hr[kt]) : "v"(lp), "i"(kt * 64) : "memory");
      }
      asm volatile("s_waitcnt vmcnt(0)" ::: "memory");
      unsigned int bad = 0;
#pragma unroll
      for (int kt = 0; kt < 16; ++kt) {
        union { half8 h; unsigned int u[4]; } c; c.h = hr[kt];
        bad |= ((c.u[0] ^ rep) | (c.u[1] ^ rep) | (c.u[2] ^ rep) | (c.u[3] ^ rep))
               & 0x00010001u;
      }
      if (!__any(bad != 0)) break;
      if (!use_mall && (++att > 128)) use_mall = 1;  // bounded escape hatch
    }
    __builtin_amdgcn_sched_barrier(0);

    // ---- MFMA: both row tiles, this K-half ----
    floatx4 a0 = {}, a1 = {};
#pragma unroll
    for (int kt = 0; kt < 16; ++kt) {
      const int koff = kt * 64 + lkg * 16;
      half8 wa = *(const half8*)((const char*)wlds + ((abase0 + koff) ^ asw));
      half8 wb = *(const half8*)((const char*)wlds + ((abase1 + koff) ^ asw));
      a0 = __builtin_amdgcn_mfma_f32_16x16x32_f16(wa, hr[kt], a0, 0, 0, 0);
      a1 = __builtin_amdgcn_mfma_f32_16x16x32_f16(wb, hr[kt], a1, 0, 0, 0);
    }

    // ---- kh partial exchange (parity-buffered), ONE syncthreads/step ----
    redlds[((p * 2 + (1 - kh)) * 2 + nt) * 64 + lane] = kh ? a0 : a1;
    __syncthreads();
    floatx4 tot = (kh ? a1 : a0) + redlds[((p * 2 + kh) * 2 + nt) * 64 + lane];

    const long o = o_nxt;
    const floatx4 xpv = xp_n;
    floatx4 hv;
#pragma unroll
    for (int v = 0; v < 4; ++v) {
      float z = tot[v] + xpv[v];
      hv[v] = 1.f - 2.f / (__expf(2.f * z) + 1.f);   // tanh(z)
    }

    if (t + 1 < S_) {
      // pack h[t+1] with LSB tag (t+1)&1; DUAL-store: local L2 + MALL.
      union { half4v h; u64 u; unsigned int w2[2]; } hh;
      hh.h = half4v{(_Float16)hv[0], (_Float16)hv[1], (_Float16)hv[2], (_Float16)hv[3]};
      const unsigned int eo = (unsigned)((t + 1) & 1) * 0x00010001u;
      hh.w2[0] = (hh.w2[0] & ~0x00010001u) | eo;
      hh.w2[1] = (hh.w2[1] & ~0x00010001u) | eo;
      u64* dl = (u64*)(hloc  + (s_out * hstride) + outoff_base);
      u64* dm = (u64*)(hmall + (s_out * hstride) + outoff_base);
      asm volatile("global_store_dwordx2 %0, %1, off" :: "v"(dl), "v"(hh.u) : "memory");
      __hip_atomic_store(dm, hh.u, __ATOMIC_RELAXED, __HIP_MEMORY_SCOPE_AGENT);
    }

    // out store + next xp prefetch (drain in background)
    *(floatx4*)(out + o) = hv;
    if (t + 1 < S_) {
      const int sidx1 = dir ? (S_ - 2 - t) : (t + 1);
      o_nxt = ((long)b_idx * S_ + sidx1) * (2 * H_) + dir * H_ + r0;
      xp_n = *(const floatx4*)(out + o_nxt);
    }
    s_in = s_out;
  }
}

// ---------------------------------------------------------------------------
extern "C" void kernel_launch(void* const* d_in, const int* in_sizes, int n_in,
                              void* d_out, int out_size, void* d_ws, size_t ws_size,
                              hipStream_t stream) {
  const float* x    = (const float*)d_in[0];
  const float* Wihf = (const float*)d_in[1];
  const float* Whhf = (const float*)d_in[2];
  const float* bihf = (const float*)d_in[3];
  const float* bhhf = (const float*)d_in[4];
  const float* Wihb = (const float*)d_in[5];
  const float* Whhb = (const float*)d_in[6];
  const float* bihb = (const float*)d_in[7];
  const float* bhhb = (const float*)d_in[8];
  float* out = (float*)d_out;

  // workspace layout
  char* ws = (char*)d_ws;
  _Float16* x16   = (_Float16*)ws;                          // 32 MiB
  _Float16* w16   = (_Float16*)(ws + 33554432u);            // 4 MiB
  float*    bias  = (float*)   (ws + 37748736u);            // 8 KiB
  _Float16* hmall = (_Float16*)(ws + 37756928u);            // 384 KiB MALL ring
  _Float16* hloc  = (_Float16*)(ws + 38150144u);            // 384 KiB local ring

  cvt_f32_f16<<<4096, 256, 0, stream>>>(x, x16, (long)M_TOT * I_);
  cvt_f32_f16<<<1024, 256, 0, stream>>>(Wihf, w16, (long)H_ * I_);
  cvt_f32_f16<<<1024, 256, 0, stream>>>(Wihb, w16 + (long)H_ * I_, (long)H_ * I_);
  bias_sum_kernel<<<4, 256, 0, stream>>>(bihf, bhhf, bihb, bhhb, bias);
  init_ring<<<768, 256, 0, stream>>>((unsigned int*)hmall);  // seeds BOTH rings

  dim3 g(H_ / 128, M_TOT / 128, 2);
  gemm_xp_kernel<<<g, 256, 0, stream>>>(x16, w16, bias, out);

  void* args[] = {(void*)&Whhf, (void*)&Whhb, (void*)&out, (void*)&hmall, (void*)&hloc};
  (void)hipLaunchCooperativeKernel((void*)scan_kernel, dim3(256), dim3(256),
                                   args, 0, stream);
}